// Round 8
// baseline (219.911 us; speedup 1.0000x reference)
//
#include <hip/hip_runtime.h>
#include <math.h>

// Problem constants (match reference)
#define ALPHA     1.0f
#define BETA      0.001f
#define GAMMA     0.1f
#define THRESH    0.5f
#define LOG_CLAMP -100.0f
#define LN2       0.69314718055994530942f

constexpr int B = 256, C = 2, H = 192, W = 256;
constexpr int HW   = H * W;          // 49152
constexpr int HW4  = HW / 4;         // 12288 float4 per (b,c) slab
constexpr long long NTOT = (long long)B * C * H * W;  // 25165824
constexpr int N4   = (int)(NTOT / 4);                  // 6291456

constexpr int BCE_BLOCKS   = 2048;   // 8 blocks/CU exact fill (32 waves/CU)
constexpr int PAIRS        = 12;     // 2048*256*12 == N4 exactly
constexpr int BATCH        = 6;      // loads kept in flight per batch
constexpr int DENSE_BLOCKS = 1024;
constexpr int FUSED_GRID   = DENSE_BLOCKS + BCE_BLOCKS;  // 3072

// Native Clang vector type.
typedef float vfloat4 __attribute__((ext_vector_type(4)));

// Hardware v_log_f32 (log2) * ln2, ~1 ulp — threshold is 6.7e3 absolute.
__device__ __forceinline__ float fast_log(float x) {
    return fmaxf(__builtin_amdgcn_logf(x) * LN2, LOG_CLAMP);
}

// ---- R14: plain loads WITH the batch shape pinned ----
// R13 post-mortem: bare *p is sinkable -> allocator flip (VGPR 32), batch
// dissolved, fused 78 us. BUT: plain loads at ~2-4 outstanding hit 3.2 TB/s
// effective where nt at the same crippled shape (R9) hit only 1.2 TB/s —
// per-request, plain loads are far more efficient. And FETCH_SIZE was
// IDENTICAL (122 MB) for nt and plain: allocation policy doesn't change the
// HBM/L3 split (poison fills control residency). So the live question is:
// plain loads at the FULL 12-burst. This kernel = byte-identical R10
// structure + plain loads + a single empty asm volatile consuming all 12
// loaded values after the load burst: every load must be issued & complete
// before the asm, so the burst + single waitcnt codegen shape and the
// 48-VGPR liveness are forced regardless of load sinkability. Zero cost.
__device__ __forceinline__ vfloat4 nt_load4(const vfloat4* p) {
    return *p;   // plain global_load_dwordx4
}

__device__ __forceinline__ float wave_reduce(float v) {
#pragma unroll
    for (int off = 32; off > 0; off >>= 1)
        v += __shfl_down(v, off, 64);
    return v;
}

__global__ __launch_bounds__(256, 8) void fused_kernel(
        const vfloat4* __restrict__ p4,
        const vfloat4* __restrict__ t4,
        const float*   __restrict__ in,
        float2* __restrict__ part_bce,
        float*  __restrict__ part_dense) {

    if (blockIdx.x < DENSE_BLOCKS) {
        // ---- dense penalty, segmented scan (R6 structure, chunked) ----
        // Hits in rows [1..190] of channel 1; consecutive hits (i,j) add
        // 1/(j-i)^3. Column split into 4 row-segments (4 waves/block),
        // merged via the associative (first, last, sum) monoid in LDS.
        const int lane = threadIdx.x & 63;
        const int seg  = threadIdx.x >> 6;            // 0..3, rows [seg*48, +48)
        const int j    = blockIdx.x * 64 + lane;      // column id, 0..65535
        const int b    = j >> 8;                      // W == 256
        const int w    = j & 255;
        const float* col = in + ((b * 2 + 1) * H) * W + w;  // channel 1
        const int segbase = seg * 48;

        int   first = -1, last = -1;
        float sum = 0.0f;
#pragma unroll
        for (int kc = 0; kc < 48; kc += 12) {
            float v[12];
#pragma unroll
            for (int k = 0; k < 12; ++k)
                v[k] = col[(segbase + kc + k) * W];
#pragma unroll
            for (int k = 0; k < 12; ++k) {
                const int i = segbase + kc + k;
                const bool m = (v[k] > THRESH) && (i != 0) && (i != 191);
                if (m) {
                    if (last >= 0) {
                        const float d = (float)(i - last);
                        sum += __builtin_amdgcn_rcpf(d * d * d);
                    } else {
                        first = i;
                    }
                    last = i;
                }
            }
        }

        __shared__ int   sfirst[256];
        __shared__ int   slast[256];
        __shared__ float ssum[256];
        sfirst[threadIdx.x] = first;
        slast[threadIdx.x]  = last;
        ssum[threadIdx.x]   = sum;
        __syncthreads();

        if (threadIdx.x < 64) {  // wave 0 merges the 4 segments of its column
            int   mlast = -1;
            float msum  = 0.0f;
#pragma unroll
            for (int s = 0; s < 4; ++s) {
                const int idx = s * 64 + threadIdx.x;
                const int f = sfirst[idx];
                if (f >= 0) {
                    if (mlast >= 0) {
                        const float d = (float)(f - mlast);
                        msum += __builtin_amdgcn_rcpf(d * d * d);
                    }
                    msum += ssum[idx];
                    mlast = slast[idx];
                }
            }
            float r = wave_reduce(msum);
            if (threadIdx.x == 0)
                part_dense[blockIdx.x] = r;
        }
    } else {
        // ---- BCE sum + channel-0 count(>0.5) — R10 loop, shape-pinned ----
        const int bid  = blockIdx.x - DENSE_BLOCKS;
        const int base = bid * (256 * PAIRS) + threadIdx.x;

        float bce  = 0.0f;
        float cuts = 0.0f;

#pragma unroll
        for (int kb = 0; kb < PAIRS; kb += BATCH) {
            vfloat4 p[BATCH], t[BATCH];
#pragma unroll
            for (int u = 0; u < BATCH; ++u) {
                p[u] = nt_load4(&p4[base + (kb + u) * 256]);
                t[u] = nt_load4(&t4[base + (kb + u) * 256]);
            }
            // Pin: all 12 loads issued & resident HERE. Forces the burst
            // codegen + 48 live data VGPRs even with sinkable plain loads.
            asm volatile("" ::
                "v"(p[0]), "v"(t[0]), "v"(p[1]), "v"(t[1]),
                "v"(p[2]), "v"(t[2]), "v"(p[3]), "v"(t[3]),
                "v"(p[4]), "v"(t[4]), "v"(p[5]), "v"(t[5]));
#pragma unroll
            for (int u = 0; u < BATCH; ++u) {
                const int f = base + (kb + u) * 256;
                const int c = (f / HW4) & 1;   // channel of this float4
#pragma unroll
                for (int e = 0; e < 4; ++e) {
                    const float pv = p[u][e];
                    const float tv = t[u][e];
                    const float lp = fast_log(pv);
                    const float lm = fast_log(1.0f - pv);
                    bce += lm + tv * (lp - lm);   // == t*lp + (1-t)*lm
                    if (c == 0)
                        cuts += (pv > THRESH ? 1.0f : 0.0f);
                }
            }
        }

        __shared__ float sb[4], sc[4];
        float rb = wave_reduce(bce);
        float rc = wave_reduce(cuts);
        const int lane = threadIdx.x & 63;
        const int wid  = threadIdx.x >> 6;
        if (lane == 0) { sb[wid] = rb; sc[wid] = rc; }
        __syncthreads();
        if (threadIdx.x == 0) {
            part_bce[bid] = make_float2(sb[0] + sb[1] + sb[2] + sb[3],
                                        sc[0] + sc[1] + sc[2] + sc[3]);
        }
    }
}

// ---- single-block reduction of all partials + final combine ----
__global__ __launch_bounds__(256) void finalize_kernel(
        const float2* __restrict__ part_bce,
        const float* __restrict__ part_dense,
        float* __restrict__ out) {
    float b = 0.0f, c = 0.0f, d = 0.0f;
    for (int i = threadIdx.x; i < BCE_BLOCKS; i += 256) {
        float2 v = part_bce[i];
        b += v.x;
        c += v.y;
    }
    for (int i = threadIdx.x; i < DENSE_BLOCKS; i += 256)
        d += part_dense[i];

    __shared__ float sb[4], sc[4], sd[4];
    float rb = wave_reduce(b);
    float rc = wave_reduce(c);
    float rd = wave_reduce(d);
    const int lane = threadIdx.x & 63;
    const int wid  = threadIdx.x >> 6;
    if (lane == 0) { sb[wid] = rb; sc[wid] = rc; sd[wid] = rd; }
    __syncthreads();
    if (threadIdx.x == 0) {
        const float bce_sum   = sb[0] + sb[1] + sb[2] + sb[3];
        const float cuts_sum  = sc[0] + sc[1] + sc[2] + sc[3];
        const float dense_sum = sd[0] + sd[1] + sd[2] + sd[3];
        const float bce = -bce_sum / (float)NTOT;
        out[0] = ALPHA * bce + BETA * cuts_sum + GAMMA * dense_sum;
    }
}

extern "C" void kernel_launch(void* const* d_in, const int* in_sizes, int n_in,
                              void* d_out, int out_size, void* d_ws, size_t ws_size,
                              hipStream_t stream) {
    const float* inputs  = (const float*)d_in[0];
    const float* targets = (const float*)d_in[1];
    float* out = (float*)d_out;

    // ws layout: [0 .. BCE_BLOCKS)  float2 bce partials
    //            then DENSE_BLOCKS float dense partials
    float2* part_bce   = (float2*)d_ws;
    float*  part_dense = (float*)d_ws + 2 * BCE_BLOCKS;

    fused_kernel<<<FUSED_GRID, 256, 0, stream>>>(
        (const vfloat4*)inputs, (const vfloat4*)targets, inputs,
        part_bce, part_dense);

    finalize_kernel<<<1, 256, 0, stream>>>(part_bce, part_dense, out);
}

// Round 10
// 210.511 us; speedup vs baseline: 1.0446x; 1.0446x over previous
//
#include <hip/hip_runtime.h>
#include <math.h>

// Problem constants (match reference)
#define ALPHA     1.0f
#define BETA      0.001f
#define GAMMA     0.1f
#define THRESH    0.5f
#define LOG_CLAMP -100.0f
#define LN2       0.69314718055994530942f

constexpr int B = 256, C = 2, H = 192, W = 256;
constexpr int HW   = H * W;          // 49152
constexpr int HW4  = HW / 4;         // 12288 float4 per (b,c) slab
constexpr long long NTOT = (long long)B * C * H * W;  // 25165824
constexpr int N4   = (int)(NTOT / 4);                  // 6291456

constexpr int BCE_BLOCKS   = 2048;   // 8 blocks/CU exact fill (32 waves/CU)
constexpr int PAIRS        = 12;     // 2048*256*12 == N4 exactly
constexpr int BATCH        = 6;      // loads kept in flight per batch
constexpr int DENSE_BLOCKS = 256;    // R15: one block per batch (float4 cols)
constexpr int FUSED_GRID   = DENSE_BLOCKS + BCE_BLOCKS;  // 2304

// Native Clang vector type — __builtin_nontemporal_load rejects HIP's float4.
typedef float vfloat4 __attribute__((ext_vector_type(4)));

// Hardware v_log_f32 (log2) * ln2, ~1 ulp — threshold is 6.7e3 absolute.
__device__ __forceinline__ float fast_log(float x) {
    return fmaxf(__builtin_amdgcn_logf(x) * LN2, LOG_CLAMP);
}

// nt RESTORED (R13/R14 post-mortem): plain *p is sinkable -> allocator
// dissolves the 12-load burst (VGPR 32, fused 78 us) and an asm pin cannot
// stop it. The nontemporal builtin is what pins the proven burst codegen.
__device__ __forceinline__ vfloat4 nt_load4(const vfloat4* p) {
    return __builtin_nontemporal_load(p);
}

__device__ __forceinline__ float wave_reduce(float v) {
#pragma unroll
    for (int off = 32; off > 0; off >>= 1)
        v += __shfl_down(v, off, 64);
    return v;
}

// ---- R15 (resubmit — infra failure, experiment unmeasured) ----
// BCE path = exact R10 (champion); dense path vectorized.
// Request accounting across R10..R14: per-CU LOAD-REQUEST throughput, not
// bytes, fits every observation (3 MLP nulls, nt/plain asymmetry). Audit:
//   BCE  : 196K wave-load instrs x 1024 B  (201 MB)
//   dense: 196K wave-load instrs x  256 B  ( 50 MB)  <- scalar loads!
// Dense issued as many requests as the whole BCE stream for 1/5 the bytes.
// R15 dense: one block per batch; each thread owns a float4 column-group
// (4 cols) x 48 rows -> 1 KB per wave-load. Total requests 393K -> 245K.
// Monoid math / rcpf / edge masks unchanged; merge moves to per-column
// cross-seg merge in LDS, then batch sum. Dense-path-only change vs R10
// (dense survived the R8 restructure without flipping the BCE allocator).
__global__ __launch_bounds__(256, 8) void fused_kernel(
        const vfloat4* __restrict__ p4,
        const vfloat4* __restrict__ t4,
        const float*   __restrict__ in,
        float2* __restrict__ part_bce,
        float*  __restrict__ part_dense) {

    if (blockIdx.x < DENSE_BLOCKS) {
        // ---- dense penalty: batch blockIdx.x, channel 1 ----
        // Hits in rows [1..190]; consecutive hits (i,j) add 1/(j-i)^3.
        // 4 waves = 4 row-segments of 48; lane owns float4 column-group.
        const int lane = threadIdx.x & 63;   // float4-col 0..63 (cols 4l..4l+3)
        const int seg  = threadIdx.x >> 6;   // rows [seg*48, seg*48+48)
        const int b    = blockIdx.x;
        const vfloat4* slab4 =
            (const vfloat4*)in + (size_t)(b * 2 + 1) * (H * 64);  // ch-1 slab
        const int segbase = seg * 48;

        int   first[4] = {-1, -1, -1, -1};
        int   last[4]  = {-1, -1, -1, -1};
        float sum[4]   = {0.0f, 0.0f, 0.0f, 0.0f};

#pragma unroll
        for (int kc = 0; kc < 48; kc += 6) {
            vfloat4 v[6];
#pragma unroll
            for (int k = 0; k < 6; ++k)
                v[k] = slab4[(segbase + kc + k) * 64 + lane];
#pragma unroll
            for (int k = 0; k < 6; ++k) {
                const int i = segbase + kc + k;
                const bool edge = (i != 0) && (i != 191);
#pragma unroll
                for (int e = 0; e < 4; ++e) {
                    if ((v[k][e] > THRESH) && edge) {
                        if (last[e] >= 0) {
                            const float d = (float)(i - last[e]);
                            sum[e] += __builtin_amdgcn_rcpf(d * d * d);
                        } else {
                            first[e] = i;
                        }
                        last[e] = i;
                    }
                }
            }
        }

        __shared__ int   sfirst[1024];
        __shared__ int   slast[1024];
        __shared__ float ssum[1024];
#pragma unroll
        for (int e = 0; e < 4; ++e) {
            sfirst[threadIdx.x * 4 + e] = first[e];
            slast[threadIdx.x * 4 + e]  = last[e];
            ssum[threadIdx.x * 4 + e]   = sum[e];
        }
        __syncthreads();

        if (threadIdx.x < 64) {  // wave 0: merge 4 segs per column, sum cols
            float colsum = 0.0f;
#pragma unroll
            for (int e = 0; e < 4; ++e) {
                int   mlast = -1;
                float msum  = 0.0f;
#pragma unroll
                for (int s = 0; s < 4; ++s) {
                    const int idx = (s * 64 + threadIdx.x) * 4 + e;
                    const int f = sfirst[idx];
                    if (f >= 0) {
                        if (mlast >= 0) {
                            const float d = (float)(f - mlast);
                            msum += __builtin_amdgcn_rcpf(d * d * d);
                        }
                        msum += ssum[idx];
                        mlast = slast[idx];
                    }
                }
                colsum += msum;
            }
            float r = wave_reduce(colsum);
            if (threadIdx.x == 0)
                part_dense[b] = r;
        }
    } else {
        // ---- BCE sum + channel-0 count(>0.5) — R6/R10 loop unchanged ----
        // Batches of 6 pairs (12 nt loads issued back-to-back, 48 VGPRs of
        // data) under the 64-VGPR budget, so the allocator keeps them in
        // flight. Do NOT couple anything into this path (R7/R9/R13 lessons).
        const int bid  = blockIdx.x - DENSE_BLOCKS;
        const int base = bid * (256 * PAIRS) + threadIdx.x;

        float bce  = 0.0f;
        float cuts = 0.0f;

#pragma unroll
        for (int kb = 0; kb < PAIRS; kb += BATCH) {
            vfloat4 p[BATCH], t[BATCH];
#pragma unroll
            for (int u = 0; u < BATCH; ++u) {
                p[u] = nt_load4(&p4[base + (kb + u) * 256]);
                t[u] = nt_load4(&t4[base + (kb + u) * 256]);
            }
#pragma unroll
            for (int u = 0; u < BATCH; ++u) {
                const int f = base + (kb + u) * 256;
                const int c = (f / HW4) & 1;   // channel of this float4
#pragma unroll
                for (int e = 0; e < 4; ++e) {
                    const float pv = p[u][e];
                    const float tv = t[u][e];
                    const float lp = fast_log(pv);
                    const float lm = fast_log(1.0f - pv);
                    bce += lm + tv * (lp - lm);   // == t*lp + (1-t)*lm
                    if (c == 0)
                        cuts += (pv > THRESH ? 1.0f : 0.0f);
                }
            }
        }

        __shared__ float sb[4], sc[4];
        float rb = wave_reduce(bce);
        float rc = wave_reduce(cuts);
        const int lane = threadIdx.x & 63;
        const int wid  = threadIdx.x >> 6;
        if (lane == 0) { sb[wid] = rb; sc[wid] = rc; }
        __syncthreads();
        if (threadIdx.x == 0) {
            part_bce[bid] = make_float2(sb[0] + sb[1] + sb[2] + sb[3],
                                        sc[0] + sc[1] + sc[2] + sc[3]);
        }
    }
}

// ---- single-block reduction of all partials + final combine ----
__global__ __launch_bounds__(256) void finalize_kernel(
        const float2* __restrict__ part_bce,
        const float* __restrict__ part_dense,
        float* __restrict__ out) {
    float b = 0.0f, c = 0.0f, d = 0.0f;
    for (int i = threadIdx.x; i < BCE_BLOCKS; i += 256) {
        float2 v = part_bce[i];
        b += v.x;
        c += v.y;
    }
    for (int i = threadIdx.x; i < DENSE_BLOCKS; i += 256)
        d += part_dense[i];

    __shared__ float sb[4], sc[4], sd[4];
    float rb = wave_reduce(b);
    float rc = wave_reduce(c);
    float rd = wave_reduce(d);
    const int lane = threadIdx.x & 63;
    const int wid  = threadIdx.x >> 6;
    if (lane == 0) { sb[wid] = rb; sc[wid] = rc; sd[wid] = rd; }
    __syncthreads();
    if (threadIdx.x == 0) {
        const float bce_sum   = sb[0] + sb[1] + sb[2] + sb[3];
        const float cuts_sum  = sc[0] + sc[1] + sc[2] + sc[3];
        const float dense_sum = sd[0] + sd[1] + sd[2] + sd[3];
        const float bce = -bce_sum / (float)NTOT;
        out[0] = ALPHA * bce + BETA * cuts_sum + GAMMA * dense_sum;
    }
}

extern "C" void kernel_launch(void* const* d_in, const int* in_sizes, int n_in,
                              void* d_out, int out_size, void* d_ws, size_t ws_size,
                              hipStream_t stream) {
    const float* inputs  = (const float*)d_in[0];
    const float* targets = (const float*)d_in[1];
    float* out = (float*)d_out;

    // ws layout: [0 .. BCE_BLOCKS)  float2 bce partials
    //            then DENSE_BLOCKS float dense partials
    float2* part_bce   = (float2*)d_ws;
    float*  part_dense = (float*)d_ws + 2 * BCE_BLOCKS;

    fused_kernel<<<FUSED_GRID, 256, 0, stream>>>(
        (const vfloat4*)inputs, (const vfloat4*)targets, inputs,
        part_bce, part_dense);

    finalize_kernel<<<1, 256, 0, stream>>>(part_bce, part_dense, out);
}

// Round 11
// 206.467 us; speedup vs baseline: 1.0651x; 1.0196x over previous
//
#include <hip/hip_runtime.h>
#include <math.h>

// Problem constants (match reference)
#define ALPHA     1.0f
#define BETA      0.001f
#define GAMMA     0.1f
#define THRESH    0.5f
#define LOG_CLAMP -100.0f
#define LN2       0.69314718055994530942f

constexpr int B = 256, C = 2, H = 192, W = 256;
constexpr int HW   = H * W;          // 49152
constexpr int HW4  = HW / 4;         // 12288 float4 per (b,c) slab
constexpr long long NTOT = (long long)B * C * H * W;  // 25165824
constexpr int N4   = (int)(NTOT / 4);                  // 6291456

constexpr int BCE_BLOCKS   = 2048;   // 8 blocks/CU exact fill (32 waves/CU)
constexpr int PAIRS        = 12;     // 2048*256*12 == N4 exactly
constexpr int BATCH        = 6;      // loads kept in flight per batch
constexpr int DENSE_BLOCKS = 1024;
constexpr int FUSED_GRID   = DENSE_BLOCKS + BCE_BLOCKS;  // 3072

// Native Clang vector type — __builtin_nontemporal_load rejects HIP's float4.
typedef float vfloat4 __attribute__((ext_vector_type(4)));

// Hardware v_log_f32 (log2) * ln2, ~1 ulp — threshold is 6.7e3 absolute.
__device__ __forceinline__ float fast_log(float x) {
    return fmaxf(__builtin_amdgcn_logf(x) * LN2, LOG_CLAMP);
}

// nt is LOAD-BEARING for codegen (R13/R14): plain *p is sinkable -> the
// allocator dissolves the 12-load burst (VGPR 32, fused 78 us); an asm pin
// cannot stop it. Keep the builtin.
__device__ __forceinline__ vfloat4 nt_load4(const vfloat4* p) {
    return __builtin_nontemporal_load(p);
}

__device__ __forceinline__ float wave_reduce(float v) {
#pragma unroll
    for (int off = 32; off > 0; off >>= 1)
        v += __shfl_down(v, off, 64);
    return v;
}

// ---- R16: exact revert to champion R10 (205.5 us, session minimum) ----
// Final evidence table (R8..R15): MLP shape x3 (burst/sustained/pipelined),
// request count (-38%), and dispatch-fold all measured NULL or regression;
// cache policy unmeasurable at source (nt pins the burst codegen). The
// fused kernel is <59.5 us and invariant to every lever; the measured
// window is dominated by harness poison fills (2 x ~60 us at 84% of HW
// peak write BW — at THEIR roofline) + reset-dispatch launch overhead.
// Structural floor: ~120 (fills) + ~25 (harness gaps) + ~55 (fused,
// pinned) + ~3.5 (finalize) ~= 205 us. This revert re-pins the champion.
__global__ __launch_bounds__(256, 8) void fused_kernel(
        const vfloat4* __restrict__ p4,
        const vfloat4* __restrict__ t4,
        const float*   __restrict__ in,
        float2* __restrict__ part_bce,
        float*  __restrict__ part_dense) {

    if (blockIdx.x < DENSE_BLOCKS) {
        // ---- dense penalty, segmented scan (R6 structure, chunked) ----
        // Hits in rows [1..190] of channel 1; consecutive hits (i,j) add
        // 1/(j-i)^3. Column split into 4 row-segments (4 waves/block),
        // merged via the associative (first, last, sum) monoid in LDS.
        const int lane = threadIdx.x & 63;
        const int seg  = threadIdx.x >> 6;            // 0..3, rows [seg*48, +48)
        const int j    = blockIdx.x * 64 + lane;      // column id, 0..65535
        const int b    = j >> 8;                      // W == 256
        const int w    = j & 255;
        const float* col = in + ((b * 2 + 1) * H) * W + w;  // channel 1
        const int segbase = seg * 48;

        int   first = -1, last = -1;
        float sum = 0.0f;
#pragma unroll
        for (int kc = 0; kc < 48; kc += 12) {
            float v[12];
#pragma unroll
            for (int k = 0; k < 12; ++k)
                v[k] = col[(segbase + kc + k) * W];
#pragma unroll
            for (int k = 0; k < 12; ++k) {
                const int i = segbase + kc + k;
                const bool m = (v[k] > THRESH) && (i != 0) && (i != 191);
                if (m) {
                    if (last >= 0) {
                        const float d = (float)(i - last);
                        sum += __builtin_amdgcn_rcpf(d * d * d);
                    } else {
                        first = i;
                    }
                    last = i;
                }
            }
        }

        __shared__ int   sfirst[256];
        __shared__ int   slast[256];
        __shared__ float ssum[256];
        sfirst[threadIdx.x] = first;
        slast[threadIdx.x]  = last;
        ssum[threadIdx.x]   = sum;
        __syncthreads();

        if (threadIdx.x < 64) {  // wave 0 merges the 4 segments of its column
            int   mlast = -1;
            float msum  = 0.0f;
#pragma unroll
            for (int s = 0; s < 4; ++s) {
                const int idx = s * 64 + threadIdx.x;
                const int f = sfirst[idx];
                if (f >= 0) {
                    if (mlast >= 0) {
                        const float d = (float)(f - mlast);
                        msum += __builtin_amdgcn_rcpf(d * d * d);
                    }
                    msum += ssum[idx];
                    mlast = slast[idx];
                }
            }
            float r = wave_reduce(msum);
            if (threadIdx.x == 0)
                part_dense[blockIdx.x] = r;
        }
    } else {
        // ---- BCE sum + channel-0 count(>0.5) — R6/R10 loop unchanged ----
        // Batches of 6 pairs (12 nt loads issued back-to-back, 48 VGPRs of
        // data) under the 64-VGPR budget, so the allocator keeps them in
        // flight. Do NOT couple anything into this path (R7/R9/R13 lessons).
        const int bid  = blockIdx.x - DENSE_BLOCKS;
        const int base = bid * (256 * PAIRS) + threadIdx.x;

        float bce  = 0.0f;
        float cuts = 0.0f;

#pragma unroll
        for (int kb = 0; kb < PAIRS; kb += BATCH) {
            vfloat4 p[BATCH], t[BATCH];
#pragma unroll
            for (int u = 0; u < BATCH; ++u) {
                p[u] = nt_load4(&p4[base + (kb + u) * 256]);
                t[u] = nt_load4(&t4[base + (kb + u) * 256]);
            }
#pragma unroll
            for (int u = 0; u < BATCH; ++u) {
                const int f = base + (kb + u) * 256;
                const int c = (f / HW4) & 1;   // channel of this float4
#pragma unroll
                for (int e = 0; e < 4; ++e) {
                    const float pv = p[u][e];
                    const float tv = t[u][e];
                    const float lp = fast_log(pv);
                    const float lm = fast_log(1.0f - pv);
                    bce += lm + tv * (lp - lm);   // == t*lp + (1-t)*lm
                    if (c == 0)
                        cuts += (pv > THRESH ? 1.0f : 0.0f);
                }
            }
        }

        __shared__ float sb[4], sc[4];
        float rb = wave_reduce(bce);
        float rc = wave_reduce(cuts);
        const int lane = threadIdx.x & 63;
        const int wid  = threadIdx.x >> 6;
        if (lane == 0) { sb[wid] = rb; sc[wid] = rc; }
        __syncthreads();
        if (threadIdx.x == 0) {
            part_bce[bid] = make_float2(sb[0] + sb[1] + sb[2] + sb[3],
                                        sc[0] + sc[1] + sc[2] + sc[3]);
        }
    }
}

// ---- single-block reduction of all partials + final combine ----
__global__ __launch_bounds__(256) void finalize_kernel(
        const float2* __restrict__ part_bce,
        const float* __restrict__ part_dense,
        float* __restrict__ out) {
    float b = 0.0f, c = 0.0f, d = 0.0f;
    for (int i = threadIdx.x; i < BCE_BLOCKS; i += 256) {
        float2 v = part_bce[i];
        b += v.x;
        c += v.y;
    }
    for (int i = threadIdx.x; i < DENSE_BLOCKS; i += 256)
        d += part_dense[i];

    __shared__ float sb[4], sc[4], sd[4];
    float rb = wave_reduce(b);
    float rc = wave_reduce(c);
    float rd = wave_reduce(d);
    const int lane = threadIdx.x & 63;
    const int wid  = threadIdx.x >> 6;
    if (lane == 0) { sb[wid] = rb; sc[wid] = rc; sd[wid] = rd; }
    __syncthreads();
    if (threadIdx.x == 0) {
        const float bce_sum   = sb[0] + sb[1] + sb[2] + sb[3];
        const float cuts_sum  = sc[0] + sc[1] + sc[2] + sc[3];
        const float dense_sum = sd[0] + sd[1] + sd[2] + sd[3];
        const float bce = -bce_sum / (float)NTOT;
        out[0] = ALPHA * bce + BETA * cuts_sum + GAMMA * dense_sum;
    }
}

extern "C" void kernel_launch(void* const* d_in, const int* in_sizes, int n_in,
                              void* d_out, int out_size, void* d_ws, size_t ws_size,
                              hipStream_t stream) {
    const float* inputs  = (const float*)d_in[0];
    const float* targets = (const float*)d_in[1];
    float* out = (float*)d_out;

    // ws layout: [0 .. BCE_BLOCKS)  float2 bce partials
    //            then DENSE_BLOCKS float dense partials
    float2* part_bce   = (float2*)d_ws;
    float*  part_dense = (float*)d_ws + 2 * BCE_BLOCKS;

    fused_kernel<<<FUSED_GRID, 256, 0, stream>>>(
        (const vfloat4*)inputs, (const vfloat4*)targets, inputs,
        part_bce, part_dense);

    finalize_kernel<<<1, 256, 0, stream>>>(part_bce, part_dense, out);
}